// Round 2
// baseline (343.645 us; speedup 1.0000x reference)
//
#include <hip/hip_runtime.h>
#include <math.h>

// Problem shapes
constexpr int B = 4, H = 16, S = 1024, D = 256, P = 64;
constexpr long long N_ROWS = (long long)B * H * S;            // 65536
// Output segment offsets (floats, concatenated in return order)
constexpr long long OFF_RT = 0;                               // routing_scores
constexpr long long SZ_RT  = N_ROWS;                          // 65536
constexpr long long OFF_OR = OFF_RT + SZ_RT;                  // optimal_routes
constexpr long long SZ_OR  = N_ROWS * (long long)S;           // 67108864
constexpr long long OFF_TW = OFF_OR + SZ_OR;                  // transfer_weights
constexpr long long SZ_TW  = 16LL * 64 * 64;                  // 65536
constexpr long long OFF_PS = OFF_TW + SZ_TW;                  // pattern_scores

typedef _Float16 half8   __attribute__((ext_vector_type(8)));
typedef _Float16 half4v  __attribute__((ext_vector_type(4)));
typedef float    floatx4 __attribute__((ext_vector_type(4)));

// LDS row stride for B tiles: 256 + 8 halves (16-B pad) keeps ds_read_b128
// 16-B aligned and balances the 16-lane fragment reads across banks.
constexpr int BSTRIDE = 264;

// R10: R9's single-kernel fusion REGRESSED (+20 us): the gemm's 66 KB LDS +
// VGPR footprint is allocated for EVERY block, so the 256 MB route-fill ran
// at 2 blocks/CU and lost ~2/3 of its store bandwidth. Decouple: K1 = gemm
// with in-block prep (keeps R9's removal of the prep-kernel dependency),
// K2 = all fills with ZERO LDS / tiny VGPR at full occupancy, keeping R9's
// fat route blocks (4096 x 64 KB instead of 65536 x 4 KB one-store blocks).
constexpr int GEMM_BLOCKS  = 512;
constexpr int SMALL_BLOCKS = 128;
constexpr int ROUTE_F4_PER_THREAD = 16;
constexpr int ROUTE_BLOCKS =
    (int)((SZ_OR / 4) / (256LL * ROUTE_F4_PER_THREAD));       // 4096

// ---------------------------------------------------------------------------
// K1: gemm + row softmax, with per-block pattern normalize/split into LDS
// (verified in R9: absmax unchanged). 512 blocks = exactly 2/CU x 256 CU.
__global__ __launch_bounds__(256) void k_gemm(
        const float* __restrict__ states,
        const float* __restrict__ pat,
        float* __restrict__ out) {
    __shared__ _Float16 smem[2 * P * BSTRIDE];                // 66 KB
    int blk = blockIdx.x;
    int tid = threadIdx.x;

    _Float16* smH = smem;
    _Float16* smL = smem + P * BSTRIDE;

    int wave = tid >> 6;
    int lane = tid & 63;

    // Phase 0: load patterns (fp32, L2-resident), normalize with folded
    // 1/T = 10, split into f16 hi/lo directly into LDS.
    #pragma unroll 4
    for (int i = 0; i < 16; ++i) {
        int p = wave * 16 + i;
        floatx4 v = ((const floatx4*)(pat + (long long)p * D))[lane];
        float ss = v.x * v.x + v.y * v.y + v.z * v.z + v.w * v.w;
        #pragma unroll
        for (int m = 1; m < 64; m <<= 1) ss += __shfl_xor(ss, m, 64);
        float scale = 10.0f / fmaxf(sqrtf(ss), 1e-12f);
        half4v hh, ll;
        #pragma unroll
        for (int j = 0; j < 4; ++j) {
            float a = v[j] * scale;
            _Float16 h = (_Float16)a;
            hh[j] = h;
            ll[j] = (_Float16)(a - (float)h);
        }
        *(half4v*)&smH[p * BSTRIDE + lane * 4] = hh;
        *(half4v*)&smL[p * BSTRIDE + lane * 4] = ll;
    }
    __syncthreads();

    // Phase 1: sims = states @ pn^T via f16 split-precision MFMA.
    // Wave tile 32 rows x 64 patterns: each LDS B-fragment pair feeds
    // 6 MFMAs. acc = 2 row sets x 4 N-tiles x 4 = 32 VGPRs.
    int q = lane >> 4;                     // quad 0..3
    int m = lane & 15;
    long long row0 = (long long)blk * 128 + wave * 32;
    const float* __restrict__ arow0 = states + (row0 + m) * D + q * 8;
    const float* __restrict__ arow1 = arow0 + 16 * D;

    floatx4 acc0[4] = {floatx4{0,0,0,0}, floatx4{0,0,0,0},
                       floatx4{0,0,0,0}, floatx4{0,0,0,0}};
    floatx4 acc1[4] = {floatx4{0,0,0,0}, floatx4{0,0,0,0},
                       floatx4{0,0,0,0}, floatx4{0,0,0,0}};

    float4 n0 = *(const float4*)(arow0);
    float4 n1 = *(const float4*)(arow0 + 4);
    float4 n2 = *(const float4*)(arow1);
    float4 n3 = *(const float4*)(arow1 + 4);
    #pragma unroll
    for (int kk = 0; kk < 8; ++kk) {
        float av0[8] = { n0.x, n0.y, n0.z, n0.w, n1.x, n1.y, n1.z, n1.w };
        float av1[8] = { n2.x, n2.y, n2.z, n2.w, n3.x, n3.y, n3.z, n3.w };
        if (kk < 7) {                                 // prefetch next A chunks
            n0 = *(const float4*)(arow0 + (kk + 1) * 32);
            n1 = *(const float4*)(arow0 + (kk + 1) * 32 + 4);
            n2 = *(const float4*)(arow1 + (kk + 1) * 32);
            n3 = *(const float4*)(arow1 + (kk + 1) * 32 + 4);
        }
        half8 ah0, al0, ah1, al1;
        #pragma unroll
        for (int j = 0; j < 8; ++j) {
            _Float16 h0 = (_Float16)av0[j];
            ah0[j] = h0;
            al0[j] = (_Float16)(av0[j] - (float)h0);
            _Float16 h1 = (_Float16)av1[j];
            ah1[j] = h1;
            al1[j] = (_Float16)(av1[j] - (float)h1);
        }
        #pragma unroll
        for (int t = 0; t < 4; ++t) {
            int boff = (t * 16 + m) * BSTRIDE + kk * 32 + q * 8;
            half8 bh = *(const half8*)&smH[boff];
            half8 bl = *(const half8*)&smL[boff];
            acc0[t] = __builtin_amdgcn_mfma_f32_16x16x32_f16(ah0, bh, acc0[t], 0, 0, 0);
            acc0[t] = __builtin_amdgcn_mfma_f32_16x16x32_f16(al0, bh, acc0[t], 0, 0, 0);
            acc0[t] = __builtin_amdgcn_mfma_f32_16x16x32_f16(ah0, bl, acc0[t], 0, 0, 0);
            acc1[t] = __builtin_amdgcn_mfma_f32_16x16x32_f16(ah1, bh, acc1[t], 0, 0, 0);
            acc1[t] = __builtin_amdgcn_mfma_f32_16x16x32_f16(al1, bh, acc1[t], 0, 0, 0);
            acc1[t] = __builtin_amdgcn_mfma_f32_16x16x32_f16(ah1, bl, acc1[t], 0, 0, 0);
        }
    }

    // Row softmax per row set: row = q*4 + r lives in the 16 lanes sharing q
    // (shuffle masks 1..8 stay in-group); lane holds 4 cols (one per N-tile).
    float* out_ps = out + OFF_PS;
    #pragma unroll
    for (int set = 0; set < 2; ++set) {
        floatx4* acc = set ? acc1 : acc0;
        long long rbase = row0 + set * 16;
        #pragma unroll
        for (int r = 0; r < 4; ++r) {
            float mx = fmaxf(fmaxf(acc[0][r], acc[1][r]),
                             fmaxf(acc[2][r], acc[3][r]));
            #pragma unroll
            for (int msk = 1; msk < 16; msk <<= 1)
                mx = fmaxf(mx, __shfl_xor(mx, msk, 64));
            float e[4];
            float s = 0.0f;
            #pragma unroll
            for (int t = 0; t < 4; ++t) { e[t] = __expf(acc[t][r] - mx); s += e[t]; }
            #pragma unroll
            for (int msk = 1; msk < 16; msk <<= 1) s += __shfl_xor(s, msk, 64);
            float inv = 1.0f / s;
            long long row = rbase + q * 4 + r;
            #pragma unroll
            for (int t = 0; t < 4; ++t) {
                out_ps[row * P + t * 16 + m] = e[t] * inv;
            }
        }
    }
}

// ---------------------------------------------------------------------------
// K2: all fills. ZERO LDS, tiny VGPR -> max occupancy for the 256 MB
// streaming store. Blocks [0,128) = small segments, [128,128+4096) = routes.
__global__ __launch_bounds__(256) void k_fill(
        const floatx4* __restrict__ tw,
        float* __restrict__ out) {
    int blk = blockIdx.x;
    int tid = threadIdx.x;

    if (blk < SMALL_BLOCKS) {
        // routing_scores = 1/1024 everywhere; tw passthrough copy
        int i = blk * 256 + tid;                              // 0..32767
        constexpr int Q = (int)(SZ_RT / 4);                   // 16384 float4
        if (i < Q) {
            floatx4 v = { 0.0009765625f, 0.0009765625f,
                          0.0009765625f, 0.0009765625f };
            ((floatx4*)(out + OFF_RT))[i] = v;
        } else {
            ((floatx4*)(out + OFF_TW))[i - Q] = tw[i - Q];
        }
        return;
    }

    // optimal_routes: d_final[j] = -j/1024, 1024-periodic, broadcast over all
    // rows. (i*4)&1023 == tid*4 for every chunk this thread writes, so the
    // float4 value is computed once and stored 16x (64 KB/block).
    long long rb = blk - SMALL_BLOCKS;                        // 0..4095
    float b0 = (float)(tid << 2) * (-0.0009765625f);
    floatx4 v;
    v.x = b0;
    v.y = b0 - 0.0009765625f;
    v.z = b0 - 0.001953125f;
    v.w = b0 - 0.0029296875f;
    floatx4* dst = (floatx4*)(out + OFF_OR)
                 + rb * (256LL * ROUTE_F4_PER_THREAD) + tid;
    #pragma unroll
    for (int k = 0; k < ROUTE_F4_PER_THREAD; ++k)
        dst[k * 256] = v;                                     // 1 KB/wave-store
}

// ---------------------------------------------------------------------------
extern "C" void kernel_launch(void* const* d_in, const int* in_sizes, int n_in,
                              void* d_out, int out_size, void* d_ws, size_t ws_size,
                              hipStream_t stream) {
    const float* states   = (const float*)d_in[0];   // (4,16,1024,256) fp32
    const float* patterns = (const float*)d_in[1];   // (64,256) fp32
    const float* transfer = (const float*)d_in[2];   // (16,64,64) fp32
    float* out = (float*)d_out;

    k_gemm<<<dim3(GEMM_BLOCKS), dim3(256), 0, stream>>>(states, patterns, out);
    k_fill<<<dim3(SMALL_BLOCKS + ROUTE_BLOCKS), dim3(256), 0, stream>>>(
        (const floatx4*)transfer, out);
}

// Round 3
// 331.675 us; speedup vs baseline: 1.0361x; 1.0361x over previous
//
#include <hip/hip_runtime.h>
#include <math.h>

// Problem shapes
constexpr int B = 4, H = 16, S = 1024, D = 256, P = 64;
constexpr long long N_ROWS = (long long)B * H * S;            // 65536
// Output segment offsets (floats, concatenated in return order)
constexpr long long OFF_RT = 0;                               // routing_scores
constexpr long long SZ_RT  = N_ROWS;                          // 65536
constexpr long long OFF_OR = OFF_RT + SZ_RT;                  // optimal_routes
constexpr long long SZ_OR  = N_ROWS * (long long)S;           // 67108864
constexpr long long OFF_TW = OFF_OR + SZ_OR;                  // transfer_weights
constexpr long long SZ_TW  = 16LL * 64 * 64;                  // 65536
constexpr long long OFF_PS = OFF_TW + SZ_TW;                  // pattern_scores

typedef _Float16 half8   __attribute__((ext_vector_type(8)));
typedef _Float16 half4v  __attribute__((ext_vector_type(4)));
typedef float    floatx4 __attribute__((ext_vector_type(4)));

// LDS row stride for B tiles: 256 + 8 halves (16-B pad) keeps ds_read_b128
// 16-B aligned and balances the 16-lane fragment reads across banks.
constexpr int BSTRIDE = 264;

// R11: R9 (fused) and R10 (decoupled, gemm-first, fat fill) were IDENTICAL
// (+21 us vs R0's 322.8) -> occupancy coupling was irrelevant; the regression
// lives in {fat strided route fill, gemm-before-fill order} (confounded in
// R9/R10). This round re-anchors on R0's exact thin fill + exact gemm and
// isolates ORDER alone: prep+small (144 blks) -> gemm -> thin route fill.
// If ~322: order innocent, fat fill guilty. If ~343: L2-dirty-poison/order
// mechanism is real and fill must run first.
constexpr int GEMM_BLOCKS   = 512;
constexpr int SMALL_BLOCKS  = 128;
constexpr int NORM_BLOCKS   = 16;
constexpr int ROUTE_BLOCKS  = 65536;                          // 1 float4/thread

// ---------------------------------------------------------------------------
// K_A: pattern normalize/split (16 blocks) + small segments (128 blocks).
__global__ __launch_bounds__(256) void k_prep_small(
        const float* __restrict__ pat,
        const floatx4* __restrict__ tw,
        float* __restrict__ out,
        _Float16* __restrict__ pnh,
        _Float16* __restrict__ pnl) {
    int blk = blockIdx.x;
    int t   = threadIdx.x;
    if (blk < SMALL_BLOCKS) {
        // routing_scores = 1/1024 everywhere; tw passthrough copy
        int i = blk * 256 + t;                                // 0..32767
        constexpr int Q = (int)(SZ_RT / 4);                   // 16384 float4
        if (i < Q) {
            floatx4 v = { 0.0009765625f, 0.0009765625f,
                          0.0009765625f, 0.0009765625f };
            ((floatx4*)(out + OFF_RT))[i] = v;
        } else {
            ((floatx4*)(out + OFF_TW))[i - Q] = tw[i - Q];
        }
        return;
    }
    // normalize: 16 blocks x 4 waves, one pattern per wave (exact R0 math:
    // folded 1/T = 10, split into f16 hi/lo, layout [p][k]).
    int p    = (blk - SMALL_BLOCKS) * 4 + (t >> 6);
    int lane = t & 63;
    const floatx4* src = (const floatx4*)(pat + (long long)p * D);
    floatx4 v = src[lane];
    float ss = v.x * v.x + v.y * v.y + v.z * v.z + v.w * v.w;
    #pragma unroll
    for (int m = 1; m < 64; m <<= 1) ss += __shfl_xor(ss, m, 64);
    float scale = 10.0f / fmaxf(sqrtf(ss), 1e-12f);
    float a[4] = { v.x * scale, v.y * scale, v.z * scale, v.w * scale };
    half4v hh, ll;
    #pragma unroll
    for (int j = 0; j < 4; ++j) {
        _Float16 h = (_Float16)a[j];
        hh[j] = h;
        ll[j] = (_Float16)(a[j] - (float)h);
    }
    *(half4v*)(pnh + (long long)p * D + lane * 4) = hh;
    *(half4v*)(pnl + (long long)p * D + lane * 4) = ll;
}

// ---------------------------------------------------------------------------
// K_B: gemm v4 (exact R0): sims = states @ pn^T via f16 split-precision MFMA
// + row softmax. Wave tile 32 rows x 64 patterns; B staged in LDS once per
// block (coalesced); acc = 2 row sets x 4 N-tiles x 4 = 32 VGPRs.
__global__ __launch_bounds__(256) void k_gemm_mfma(
        const float* __restrict__ states,
        const _Float16* __restrict__ pnh,
        const _Float16* __restrict__ pnl,
        float* __restrict__ out_ps) {
    __shared__ _Float16 smem[2 * P * BSTRIDE];       // Bh then Bl
    _Float16* smH = smem;
    _Float16* smL = smem + P * BSTRIDE;

    int tid  = threadIdx.x;
    // --- Phase 0: stage B into LDS (coalesced) -----------------------------
    {
        const half8* gh = (const half8*)pnh;         // 2048 x 16 B chunks
        const half8* gl = (const half8*)pnl;
        #pragma unroll
        for (int it = 0; it < 8; ++it) {
            int idx = it * 256 + tid;
            int row = idx >> 5;                      // pattern row
            int c8  = idx & 31;                      // 8-half chunk in row
            *(half8*)&smH[row * BSTRIDE + c8 * 8] = gh[idx];
            *(half8*)&smL[row * BSTRIDE + c8 * 8] = gl[idx];
        }
    }
    __syncthreads();

    int wave = tid >> 6;
    int lane = tid & 63;
    int q    = lane >> 4;                  // quad 0..3
    int m    = lane & 15;
    long long row0 = (long long)blockIdx.x * 128 + wave * 32;
    const float* __restrict__ arow0 = states + (row0 + m) * D + q * 8;
    const float* __restrict__ arow1 = arow0 + 16 * D;

    floatx4 acc0[4] = {floatx4{0,0,0,0}, floatx4{0,0,0,0},
                       floatx4{0,0,0,0}, floatx4{0,0,0,0}};
    floatx4 acc1[4] = {floatx4{0,0,0,0}, floatx4{0,0,0,0},
                       floatx4{0,0,0,0}, floatx4{0,0,0,0}};

    float4 n0 = *(const float4*)(arow0);
    float4 n1 = *(const float4*)(arow0 + 4);
    float4 n2 = *(const float4*)(arow1);
    float4 n3 = *(const float4*)(arow1 + 4);
    #pragma unroll
    for (int kk = 0; kk < 8; ++kk) {
        float av0[8] = { n0.x, n0.y, n0.z, n0.w, n1.x, n1.y, n1.z, n1.w };
        float av1[8] = { n2.x, n2.y, n2.z, n2.w, n3.x, n3.y, n3.z, n3.w };
        if (kk < 7) {                                 // prefetch next A chunks
            n0 = *(const float4*)(arow0 + (kk + 1) * 32);
            n1 = *(const float4*)(arow0 + (kk + 1) * 32 + 4);
            n2 = *(const float4*)(arow1 + (kk + 1) * 32);
            n3 = *(const float4*)(arow1 + (kk + 1) * 32 + 4);
        }
        half8 ah0, al0, ah1, al1;
        #pragma unroll
        for (int j = 0; j < 8; ++j) {
            _Float16 h0 = (_Float16)av0[j];
            ah0[j] = h0;
            al0[j] = (_Float16)(av0[j] - (float)h0);
            _Float16 h1 = (_Float16)av1[j];
            ah1[j] = h1;
            al1[j] = (_Float16)(av1[j] - (float)h1);
        }
        #pragma unroll
        for (int t = 0; t < 4; ++t) {
            int boff = (t * 16 + m) * BSTRIDE + kk * 32 + q * 8;
            half8 bh = *(const half8*)&smH[boff];
            half8 bl = *(const half8*)&smL[boff];
            acc0[t] = __builtin_amdgcn_mfma_f32_16x16x32_f16(ah0, bh, acc0[t], 0, 0, 0);
            acc0[t] = __builtin_amdgcn_mfma_f32_16x16x32_f16(al0, bh, acc0[t], 0, 0, 0);
            acc0[t] = __builtin_amdgcn_mfma_f32_16x16x32_f16(ah0, bl, acc0[t], 0, 0, 0);
            acc1[t] = __builtin_amdgcn_mfma_f32_16x16x32_f16(ah1, bh, acc1[t], 0, 0, 0);
            acc1[t] = __builtin_amdgcn_mfma_f32_16x16x32_f16(al1, bh, acc1[t], 0, 0, 0);
            acc1[t] = __builtin_amdgcn_mfma_f32_16x16x32_f16(ah1, bl, acc1[t], 0, 0, 0);
        }
    }

    // Row softmax per row set: row = q*4 + r lives in the 16 lanes sharing q
    // (shuffle masks 1..8 stay in-group); lane holds 4 cols (one per N-tile).
    #pragma unroll
    for (int set = 0; set < 2; ++set) {
        floatx4* acc = set ? acc1 : acc0;
        long long rbase = row0 + set * 16;
        #pragma unroll
        for (int r = 0; r < 4; ++r) {
            float mx = fmaxf(fmaxf(acc[0][r], acc[1][r]),
                             fmaxf(acc[2][r], acc[3][r]));
            #pragma unroll
            for (int msk = 1; msk < 16; msk <<= 1)
                mx = fmaxf(mx, __shfl_xor(mx, msk, 64));
            float e[4];
            float s = 0.0f;
            #pragma unroll
            for (int t = 0; t < 4; ++t) { e[t] = __expf(acc[t][r] - mx); s += e[t]; }
            #pragma unroll
            for (int msk = 1; msk < 16; msk <<= 1) s += __shfl_xor(s, msk, 64);
            float inv = 1.0f / s;
            long long row = rbase + q * 4 + r;
            #pragma unroll
            for (int t = 0; t < 4; ++t) {
                out_ps[row * P + t * 16 + m] = e[t] * inv;
            }
        }
    }
}

// ---------------------------------------------------------------------------
// K_C: optimal_routes fill — EXACT R0 pattern: 65536 blocks, one contiguous
// float4 store per thread (4 KB/block).
__global__ __launch_bounds__(256) void k_route_fill(
        floatx4* __restrict__ routes) {
    long long i = (long long)blockIdx.x * 256 + threadIdx.x;
    int j0 = (int)((i << 2) & (S - 1));              // 1024-periodic column
    float b0 = (float)j0 * (-0.0009765625f);
    floatx4 v;
    v.x = b0;
    v.y = b0 - 0.0009765625f;
    v.z = b0 - 0.001953125f;
    v.w = b0 - 0.0029296875f;
    routes[i] = v;
}

// ---------------------------------------------------------------------------
extern "C" void kernel_launch(void* const* d_in, const int* in_sizes, int n_in,
                              void* d_out, int out_size, void* d_ws, size_t ws_size,
                              hipStream_t stream) {
    const float* states   = (const float*)d_in[0];   // (4,16,1024,256) fp32
    const float* patterns = (const float*)d_in[1];   // (64,256) fp32
    const float* transfer = (const float*)d_in[2];   // (16,64,64) fp32
    float* out = (float*)d_out;
    _Float16* pnh = (_Float16*)d_ws;                 // 64*256 halves = 32 KB
    _Float16* pnl = pnh + P * D;                     // +32 KB

    k_prep_small<<<dim3(SMALL_BLOCKS + NORM_BLOCKS), dim3(256), 0, stream>>>(
        patterns, (const floatx4*)transfer, out, pnh, pnl);
    k_gemm_mfma<<<dim3(GEMM_BLOCKS), dim3(256), 0, stream>>>(
        states, pnh, pnl, out + OFF_PS);
    k_route_fill<<<dim3(ROUTE_BLOCKS), dim3(256), 0, stream>>>(
        (floatx4*)(out + OFF_OR));
}

// Round 4
// 328.440 us; speedup vs baseline: 1.0463x; 1.0098x over previous
//
#include <hip/hip_runtime.h>
#include <math.h>

// Problem shapes
constexpr int B = 4, H = 16, S = 1024, D = 256, P = 64;
constexpr long long N_ROWS = (long long)B * H * S;            // 65536
// Output segment offsets (floats, concatenated in return order)
constexpr long long OFF_RT = 0;                               // routing_scores
constexpr long long SZ_RT  = N_ROWS;                          // 65536
constexpr long long OFF_OR = OFF_RT + SZ_RT;                  // optimal_routes
constexpr long long SZ_OR  = N_ROWS * (long long)S;           // 67108864
constexpr long long OFF_TW = OFF_OR + SZ_OR;                  // transfer_weights
constexpr long long SZ_TW  = 16LL * 64 * 64;                  // 65536
constexpr long long OFF_PS = OFF_TW + SZ_TW;                  // pattern_scores

typedef _Float16 half8   __attribute__((ext_vector_type(8)));
typedef _Float16 half4v  __attribute__((ext_vector_type(4)));
typedef float    floatx4 __attribute__((ext_vector_type(4)));

// LDS row stride for B tiles: 256 + 8 halves (16-B pad) keeps ds_read_b128
// 16-B aligned and balances the 16-lane fragment reads across banks.
constexpr int BSTRIDE = 264;

// R12: isolation complete. R0..R3 showed two additive effects: fill-first
// beats gemm-first by ~9 us, thin fill beats fat fill by ~12 us; and R1==R2
// proved overlap/occupancy of the fill are irrelevant (aggregate is BW +
// per-launch overhead). This round = R0's exact byte streams (thin fill
// FIRST, then small, then gemm) collapsed into ONE launch to remove a
// kernel boundary. Gemm blocks sit at the END of the grid so the CP
// dispatches all fill blocks first (preserves R0's winning order); gemm
// uses the R9-verified in-block pattern prep (no prep kernel, no ws).
constexpr int ROUTE_BLOCKS  = 65536;                          // thin: 1 f4/thread
constexpr int SMALL_BLOCKS  = 128;
constexpr int GEMM_BLOCKS   = 512;

__global__ __launch_bounds__(256) void k_all(
        const float* __restrict__ states,
        const float* __restrict__ pat,
        const floatx4* __restrict__ tw,
        float* __restrict__ out) {
    __shared__ _Float16 smem[2 * P * BSTRIDE];                // 66 KB
    int blk = blockIdx.x;
    int tid = threadIdx.x;

    if (blk < ROUTE_BLOCKS) {
        // optimal_routes: EXACT R0 thin pattern — one contiguous float4
        // store per thread (4 KB/block). d_final[j] = -j/1024, periodic.
        long long i = (long long)blk * 256 + tid;
        int j0 = (int)((i << 2) & (S - 1));                   // periodic col
        float b0 = (float)j0 * (-0.0009765625f);
        floatx4 v;
        v.x = b0;
        v.y = b0 - 0.0009765625f;
        v.z = b0 - 0.001953125f;
        v.w = b0 - 0.0029296875f;
        ((floatx4*)(out + OFF_OR))[i] = v;
        return;
    }
    if (blk < ROUTE_BLOCKS + SMALL_BLOCKS) {
        // routing_scores = 1/1024 everywhere; tw passthrough copy
        int i = (blk - ROUTE_BLOCKS) * 256 + tid;             // 0..32767
        constexpr int Q = (int)(SZ_RT / 4);                   // 16384 float4
        if (i < Q) {
            floatx4 v = { 0.0009765625f, 0.0009765625f,
                          0.0009765625f, 0.0009765625f };
            ((floatx4*)(out + OFF_RT))[i] = v;
        } else {
            ((floatx4*)(out + OFF_TW))[i - Q] = tw[i - Q];
        }
        return;
    }

    // ---------------- GEMM + row softmax (last 512 blocks) -----------------
    int gb = blk - ROUTE_BLOCKS - SMALL_BLOCKS;
    _Float16* smH = smem;
    _Float16* smL = smem + P * BSTRIDE;

    int wave = tid >> 6;
    int lane = tid & 63;

    // Phase 0 (R9-verified): load patterns (fp32, L2-resident), normalize
    // with folded 1/T = 10, split into f16 hi/lo directly into LDS.
    #pragma unroll 4
    for (int i = 0; i < 16; ++i) {
        int p = wave * 16 + i;
        floatx4 v = ((const floatx4*)(pat + (long long)p * D))[lane];
        float ss = v.x * v.x + v.y * v.y + v.z * v.z + v.w * v.w;
        #pragma unroll
        for (int m = 1; m < 64; m <<= 1) ss += __shfl_xor(ss, m, 64);
        float scale = 10.0f / fmaxf(sqrtf(ss), 1e-12f);
        half4v hh, ll;
        #pragma unroll
        for (int j = 0; j < 4; ++j) {
            float a = v[j] * scale;
            _Float16 h = (_Float16)a;
            hh[j] = h;
            ll[j] = (_Float16)(a - (float)h);
        }
        *(half4v*)&smH[p * BSTRIDE + lane * 4] = hh;
        *(half4v*)&smL[p * BSTRIDE + lane * 4] = ll;
    }
    __syncthreads();

    // Phase 1: sims = states @ pn^T via f16 split-precision MFMA.
    // Wave tile 32 rows x 64 patterns; acc = 2 sets x 4 N-tiles x 4 = 32.
    int q = lane >> 4;                     // quad 0..3
    int m = lane & 15;
    long long row0 = (long long)gb * 128 + wave * 32;
    const float* __restrict__ arow0 = states + (row0 + m) * D + q * 8;
    const float* __restrict__ arow1 = arow0 + 16 * D;

    floatx4 acc0[4] = {floatx4{0,0,0,0}, floatx4{0,0,0,0},
                       floatx4{0,0,0,0}, floatx4{0,0,0,0}};
    floatx4 acc1[4] = {floatx4{0,0,0,0}, floatx4{0,0,0,0},
                       floatx4{0,0,0,0}, floatx4{0,0,0,0}};

    float4 n0 = *(const float4*)(arow0);
    float4 n1 = *(const float4*)(arow0 + 4);
    float4 n2 = *(const float4*)(arow1);
    float4 n3 = *(const float4*)(arow1 + 4);
    #pragma unroll
    for (int kk = 0; kk < 8; ++kk) {
        float av0[8] = { n0.x, n0.y, n0.z, n0.w, n1.x, n1.y, n1.z, n1.w };
        float av1[8] = { n2.x, n2.y, n2.z, n2.w, n3.x, n3.y, n3.z, n3.w };
        if (kk < 7) {                                 // prefetch next A chunks
            n0 = *(const float4*)(arow0 + (kk + 1) * 32);
            n1 = *(const float4*)(arow0 + (kk + 1) * 32 + 4);
            n2 = *(const float4*)(arow1 + (kk + 1) * 32);
            n3 = *(const float4*)(arow1 + (kk + 1) * 32 + 4);
        }
        half8 ah0, al0, ah1, al1;
        #pragma unroll
        for (int j = 0; j < 8; ++j) {
            _Float16 h0 = (_Float16)av0[j];
            ah0[j] = h0;
            al0[j] = (_Float16)(av0[j] - (float)h0);
            _Float16 h1 = (_Float16)av1[j];
            ah1[j] = h1;
            al1[j] = (_Float16)(av1[j] - (float)h1);
        }
        #pragma unroll
        for (int t = 0; t < 4; ++t) {
            int boff = (t * 16 + m) * BSTRIDE + kk * 32 + q * 8;
            half8 bh = *(const half8*)&smH[boff];
            half8 bl = *(const half8*)&smL[boff];
            acc0[t] = __builtin_amdgcn_mfma_f32_16x16x32_f16(ah0, bh, acc0[t], 0, 0, 0);
            acc0[t] = __builtin_amdgcn_mfma_f32_16x16x32_f16(al0, bh, acc0[t], 0, 0, 0);
            acc0[t] = __builtin_amdgcn_mfma_f32_16x16x32_f16(ah0, bl, acc0[t], 0, 0, 0);
            acc1[t] = __builtin_amdgcn_mfma_f32_16x16x32_f16(ah1, bh, acc1[t], 0, 0, 0);
            acc1[t] = __builtin_amdgcn_mfma_f32_16x16x32_f16(al1, bh, acc1[t], 0, 0, 0);
            acc1[t] = __builtin_amdgcn_mfma_f32_16x16x32_f16(ah1, bl, acc1[t], 0, 0, 0);
        }
    }

    // Row softmax per row set: row = q*4 + r lives in the 16 lanes sharing q
    // (shuffle masks 1..8 stay in-group); lane holds 4 cols (one per N-tile).
    float* out_ps = out + OFF_PS;
    #pragma unroll
    for (int set = 0; set < 2; ++set) {
        floatx4* acc = set ? acc1 : acc0;
        long long rbase = row0 + set * 16;
        #pragma unroll
        for (int r = 0; r < 4; ++r) {
            float mx = fmaxf(fmaxf(acc[0][r], acc[1][r]),
                             fmaxf(acc[2][r], acc[3][r]));
            #pragma unroll
            for (int msk = 1; msk < 16; msk <<= 1)
                mx = fmaxf(mx, __shfl_xor(mx, msk, 64));
            float e[4];
            float s = 0.0f;
            #pragma unroll
            for (int t = 0; t < 4; ++t) { e[t] = __expf(acc[t][r] - mx); s += e[t]; }
            #pragma unroll
            for (int msk = 1; msk < 16; msk <<= 1) s += __shfl_xor(s, msk, 64);
            float inv = 1.0f / s;
            long long row = rbase + q * 4 + r;
            #pragma unroll
            for (int t = 0; t < 4; ++t) {
                out_ps[row * P + t * 16 + m] = e[t] * inv;
            }
        }
    }
}

// ---------------------------------------------------------------------------
extern "C" void kernel_launch(void* const* d_in, const int* in_sizes, int n_in,
                              void* d_out, int out_size, void* d_ws, size_t ws_size,
                              hipStream_t stream) {
    const float* states   = (const float*)d_in[0];   // (4,16,1024,256) fp32
    const float* patterns = (const float*)d_in[1];   // (64,256) fp32
    const float* transfer = (const float*)d_in[2];   // (16,64,64) fp32
    float* out = (float*)d_out;

    k_all<<<dim3(ROUTE_BLOCKS + SMALL_BLOCKS + GEMM_BLOCKS), dim3(256), 0,
            stream>>>(states, patterns, (const floatx4*)transfer, out);
}

// Round 5
// 326.411 us; speedup vs baseline: 1.0528x; 1.0062x over previous
//
#include <hip/hip_runtime.h>
#include <math.h>

// Problem shapes
constexpr int B = 4, H = 16, S = 1024, D = 256, P = 64;
constexpr long long N_ROWS = (long long)B * H * S;            // 65536
// Output segment offsets (floats, concatenated in return order)
constexpr long long OFF_RT = 0;                               // routing_scores
constexpr long long SZ_RT  = N_ROWS;                          // 65536
constexpr long long OFF_OR = OFF_RT + SZ_RT;                  // optimal_routes
constexpr long long SZ_OR  = N_ROWS * (long long)S;           // 67108864
constexpr long long OFF_TW = OFF_OR + SZ_OR;                  // transfer_weights
constexpr long long SZ_TW  = 16LL * 64 * 64;                  // 65536
constexpr long long OFF_PS = OFF_TW + SZ_TW;                  // pattern_scores

typedef _Float16 half8   __attribute__((ext_vector_type(8)));
typedef _Float16 half4v  __attribute__((ext_vector_type(4)));
typedef float    floatx4 __attribute__((ext_vector_type(4)));

// LDS row stride for B tiles: 256 + 8 halves (16-B pad) keeps ds_read_b128
// 16-B aligned and balances the 16-lane fragment reads across banks.
constexpr int BSTRIDE = 264;

// R13: REVERT to the R0 anchor exactly. Session experiment matrix (R9-R12)
// isolated three additive effects and R0 is optimal on all three:
//   - fill BEFORE gemm:            gemm-first costs ~+9 us  (R3 vs R0)
//   - thin contiguous route fill:  fat strided costs ~+12 us (R2 vs R3)
//   - thin fill needs full occ:    66KB-LDS coupling costs ~+5.6 us (R4 vs R0)
// Single-launch fusion is structurally blocked (LDS/VGPR are per-kernel, so
// fill occupancy and gemm LDS cannot decouple). Two launches, fill-first,
// zero-LDS fill kernel at max occupancy + MFMA gemm kernel = best measured.

// ---------------------------------------------------------------------------
// Kernel 1 (fused fill + prep): 65536 route blocks, 128 small-segment blocks,
// 16 normalize blocks.
__global__ __launch_bounds__(256) void k_fill_prep(
        floatx4* __restrict__ routes,
        const floatx4* __restrict__ tw,
        float* __restrict__ out,
        const float* __restrict__ pat,
        _Float16* __restrict__ pnh,
        _Float16* __restrict__ pnl) {
    long long blk = blockIdx.x;
    int t = threadIdx.x;
    if (blk < 65536) {
        long long i = blk * 256 + t;
        int j0 = (int)((i << 2) & (S - 1));          // 1024-periodic column
        float b0 = (float)j0 * (-0.0009765625f);
        floatx4 v;
        v.x = b0;
        v.y = b0 - 0.0009765625f;
        v.z = b0 - 0.001953125f;
        v.w = b0 - 0.0029296875f;
        routes[i] = v;
    } else if (blk < 65536 + 128) {
        int i = (int)(blk - 65536) * 256 + t;        // 0..32767
        constexpr int Q = (int)SZ_RT / 4;            // 16384 float4 / segment
        if (i < Q) {
            floatx4 v = { 0.0009765625f, 0.0009765625f,
                          0.0009765625f, 0.0009765625f };
            ((floatx4*)(out + OFF_RT))[i] = v;
        } else {
            ((floatx4*)(out + OFF_TW))[i - Q] = tw[i - Q];
        }
    } else {
        // normalize: 16 blocks x 4 waves, one pattern per wave
        int p    = (int)(blk - 65536 - 128) * 4 + (t >> 6);
        int lane = t & 63;
        const floatx4* src = (const floatx4*)(pat + (long long)p * D);
        floatx4 v = src[lane];
        float ss = v.x * v.x + v.y * v.y + v.z * v.z + v.w * v.w;
        #pragma unroll
        for (int m = 1; m < 64; m <<= 1) ss += __shfl_xor(ss, m, 64);
        float scale = 10.0f / fmaxf(sqrtf(ss), 1e-12f);
        float a[4] = { v.x * scale, v.y * scale, v.z * scale, v.w * scale };
        half4v hh, ll;
        #pragma unroll
        for (int j = 0; j < 4; ++j) {
            _Float16 h = (_Float16)a[j];
            hh[j] = h;
            ll[j] = (_Float16)(a[j] - (float)h);
        }
        *(half4v*)(pnh + (long long)p * D + lane * 4) = hh;
        *(half4v*)(pnl + (long long)p * D + lane * 4) = ll;
    }
}

// ---------------------------------------------------------------------------
// Kernel 2 (gemm v4): sims = states @ pn^T via f16 split-precision MFMA +
// row softmax. Wave tile 32 rows x 64 patterns (128-row blocks, 512 blocks);
// each LDS B-fragment pair feeds 6 MFMAs. B staged in LDS once per block
// (coalesced). acc = 2 row sets x 4 N-tiles x 4 = 32 VGPRs.
__global__ __launch_bounds__(256) void k_gemm_mfma(
        const float* __restrict__ states,
        const _Float16* __restrict__ pnh,
        const _Float16* __restrict__ pnl,
        float* __restrict__ out_ps) {
    __shared__ _Float16 smem[2 * P * BSTRIDE];       // Bh then Bl
    _Float16* smH = smem;
    _Float16* smL = smem + P * BSTRIDE;

    int tid  = threadIdx.x;
    // --- Phase 0: stage B into LDS (coalesced) -----------------------------
    {
        const half8* gh = (const half8*)pnh;         // 2048 x 16 B chunks
        const half8* gl = (const half8*)pnl;
        #pragma unroll
        for (int it = 0; it < 8; ++it) {
            int idx = it * 256 + tid;
            int row = idx >> 5;                      // pattern row
            int c8  = idx & 31;                      // 8-half chunk in row
            *(half8*)&smH[row * BSTRIDE + c8 * 8] = gh[idx];
            *(half8*)&smL[row * BSTRIDE + c8 * 8] = gl[idx];
        }
    }
    __syncthreads();

    int wave = tid >> 6;
    int lane = tid & 63;
    int q    = lane >> 4;                  // quad 0..3
    int m    = lane & 15;
    long long row0 = (long long)blockIdx.x * 128 + wave * 32;
    const float* __restrict__ arow0 = states + (row0 + m) * D + q * 8;
    const float* __restrict__ arow1 = arow0 + 16 * D;

    floatx4 acc0[4] = {floatx4{0,0,0,0}, floatx4{0,0,0,0},
                       floatx4{0,0,0,0}, floatx4{0,0,0,0}};
    floatx4 acc1[4] = {floatx4{0,0,0,0}, floatx4{0,0,0,0},
                       floatx4{0,0,0,0}, floatx4{0,0,0,0}};

    float4 n0 = *(const float4*)(arow0);
    float4 n1 = *(const float4*)(arow0 + 4);
    float4 n2 = *(const float4*)(arow1);
    float4 n3 = *(const float4*)(arow1 + 4);
    #pragma unroll
    for (int kk = 0; kk < 8; ++kk) {
        float av0[8] = { n0.x, n0.y, n0.z, n0.w, n1.x, n1.y, n1.z, n1.w };
        float av1[8] = { n2.x, n2.y, n2.z, n2.w, n3.x, n3.y, n3.z, n3.w };
        if (kk < 7) {                                 // prefetch next A chunks
            n0 = *(const float4*)(arow0 + (kk + 1) * 32);
            n1 = *(const float4*)(arow0 + (kk + 1) * 32 + 4);
            n2 = *(const float4*)(arow1 + (kk + 1) * 32);
            n3 = *(const float4*)(arow1 + (kk + 1) * 32 + 4);
        }
        half8 ah0, al0, ah1, al1;
        #pragma unroll
        for (int j = 0; j < 8; ++j) {
            _Float16 h0 = (_Float16)av0[j];
            ah0[j] = h0;
            al0[j] = (_Float16)(av0[j] - (float)h0);
            _Float16 h1 = (_Float16)av1[j];
            ah1[j] = h1;
            al1[j] = (_Float16)(av1[j] - (float)h1);
        }
        #pragma unroll
        for (int t = 0; t < 4; ++t) {
            int boff = (t * 16 + m) * BSTRIDE + kk * 32 + q * 8;
            half8 bh = *(const half8*)&smH[boff];
            half8 bl = *(const half8*)&smL[boff];
            acc0[t] = __builtin_amdgcn_mfma_f32_16x16x32_f16(ah0, bh, acc0[t], 0, 0, 0);
            acc0[t] = __builtin_amdgcn_mfma_f32_16x16x32_f16(al0, bh, acc0[t], 0, 0, 0);
            acc0[t] = __builtin_amdgcn_mfma_f32_16x16x32_f16(ah0, bl, acc0[t], 0, 0, 0);
            acc1[t] = __builtin_amdgcn_mfma_f32_16x16x32_f16(ah1, bh, acc1[t], 0, 0, 0);
            acc1[t] = __builtin_amdgcn_mfma_f32_16x16x32_f16(al1, bh, acc1[t], 0, 0, 0);
            acc1[t] = __builtin_amdgcn_mfma_f32_16x16x32_f16(ah1, bl, acc1[t], 0, 0, 0);
        }
    }

    // Row softmax per row set: row = q*4 + r lives in the 16 lanes sharing q
    // (shuffle masks 1..8 stay in-group); lane holds 4 cols (one per N-tile).
    #pragma unroll
    for (int set = 0; set < 2; ++set) {
        floatx4* acc = set ? acc1 : acc0;
        long long rbase = row0 + set * 16;
        #pragma unroll
        for (int r = 0; r < 4; ++r) {
            float mx = fmaxf(fmaxf(acc[0][r], acc[1][r]),
                             fmaxf(acc[2][r], acc[3][r]));
            #pragma unroll
            for (int msk = 1; msk < 16; msk <<= 1)
                mx = fmaxf(mx, __shfl_xor(mx, msk, 64));
            float e[4];
            float s = 0.0f;
            #pragma unroll
            for (int t = 0; t < 4; ++t) { e[t] = __expf(acc[t][r] - mx); s += e[t]; }
            #pragma unroll
            for (int msk = 1; msk < 16; msk <<= 1) s += __shfl_xor(s, msk, 64);
            float inv = 1.0f / s;
            long long row = rbase + q * 4 + r;
            #pragma unroll
            for (int t = 0; t < 4; ++t) {
                out_ps[row * P + t * 16 + m] = e[t] * inv;
            }
        }
    }
}

// ---------------------------------------------------------------------------
extern "C" void kernel_launch(void* const* d_in, const int* in_sizes, int n_in,
                              void* d_out, int out_size, void* d_ws, size_t ws_size,
                              hipStream_t stream) {
    const float* states   = (const float*)d_in[0];   // (4,16,1024,256) fp32
    const float* patterns = (const float*)d_in[1];   // (64,256) fp32
    const float* transfer = (const float*)d_in[2];   // (16,64,64) fp32
    float* out = (float*)d_out;
    _Float16* pnh = (_Float16*)d_ws;                 // 64*256 halves = 32 KB
    _Float16* pnl = pnh + P * D;                     // +32 KB

    k_fill_prep<<<dim3(65536 + 128 + 16), dim3(256), 0, stream>>>(
        (floatx4*)(out + OFF_OR), (const floatx4*)transfer, out,
        patterns, pnh, pnl);

    k_gemm_mfma<<<dim3(512), dim3(256), 0, stream>>>(states, pnh, pnl, out + OFF_PS);
}